// Round 14
// baseline (292.491 us; speedup 1.0000x reference)
//
#include <hip/hip_runtime.h>

// ---------------------------------------------------------------------------
// Swin block: LN1 -> shift+window -> QKV -> win-attn(+relbias+mask) -> proj
//             -> reverse+residual -> LN2 -> MLP1(GELU) -> MLP2 + residual
// B=16 H=W=64 C=256 WS=8 SHIFT=4 HEADS=8 HD=32 N=64 HID=1024
// Round 12: WRITE-PATH fix. R6-R11 model that closes: every GEMM is
//           store-transaction-bound (~1.5 TB/s; C^T epilogue = 8B/lane over
//           16 rows -> 4x L2 write txns). New epilogue: stage output tile in
//           LDS (reuse ring buffers, XOR-swizzled), barrier, read back
//           contiguous 16B/lane -> full-line dwordx4 stores (4x256B/wave).
//           Residual reads coalesce the same way.
// ---------------------------------------------------------------------------

typedef __attribute__((ext_vector_type(8))) short bf16x8;
typedef __attribute__((ext_vector_type(4))) float f32x4;
typedef __attribute__((ext_vector_type(16))) float f32x16;

__device__ __forceinline__ float bf2f(unsigned short h) {
    union { unsigned int u; float f; } c; c.u = ((unsigned int)h) << 16; return c.f;
}
__device__ __forceinline__ unsigned short f2bf(float f) {
    union { float f; unsigned int u; } c; c.f = f;
    unsigned int u = c.u;
    return (unsigned short)((u + 0x7FFFu + ((u >> 16) & 1u)) >> 16);
}
__device__ __forceinline__ unsigned int cvtpk_bf16(float lo, float hi) {
    unsigned int r;
    asm volatile("v_cvt_pk_bf16_f32 %0, %1, %2" : "=v"(r) : "v"(lo), "v"(hi));
    return r;
}
__device__ __forceinline__ void perm32swap(unsigned int& a, unsigned int& b) {
    asm volatile("v_permlane32_swap_b32 %0, %1" : "+v"(a), "+v"(b));
}
// window-order row (b, wi, wj, r, cc) -> pixel-order row (b, hp, wp).
__device__ __forceinline__ int remap_row(int row) {
    int b  = row >> 12;
    int w6 = (row >> 6) & 63;
    int n  = row & 63;
    int hp = (((w6 >> 3) << 3) + (n >> 3) + 4) & 63;
    int wp = (((w6 & 7) << 3) + (n & 7) + 4) & 63;
    return (b << 12) | (hp << 6) | wp;
}
// gelu(v) = v * sigmoid(2c(v + 0.044715 v^3)), c = sqrt(2/pi)
__device__ __forceinline__ float gelu_f(float v) {
    float u = 1.5957691216057308f * (v + 0.044715f * v * v * v);
    return v / (1.0f + __expf(-u));
}
__device__ __forceinline__ void gload16(const unsigned short* g, unsigned short* l) {
    __builtin_amdgcn_global_load_lds(
        (const __attribute__((address_space(1))) void*)g,
        (__attribute__((address_space(3))) void*)l, 16, 0, 0);
}

// ---- LayerNorm over C=256; one wave per row; optional gather remap --------
template<int INBF>
__global__ __launch_bounds__(256) void ln_kernel(
    const void* __restrict__ inp, const float* __restrict__ g,
    const float* __restrict__ b, unsigned short* __restrict__ out, int remap)
{
    int wave = threadIdx.x >> 6, lane = threadIdx.x & 63;
    int row = (blockIdx.x << 2) + wave;
    int src = remap ? remap_row(row) : row;
    float4 xv;
    if (INBF) {
        ushort4 u = *(const ushort4*)((const unsigned short*)inp + (size_t)src * 256 + (lane << 2));
        xv.x = bf2f(u.x); xv.y = bf2f(u.y); xv.z = bf2f(u.z); xv.w = bf2f(u.w);
    } else {
        xv = *(const float4*)((const float*)inp + (size_t)src * 256 + (lane << 2));
    }
    float s  = xv.x + xv.y + xv.z + xv.w;
    float ss = xv.x*xv.x + xv.y*xv.y + xv.z*xv.z + xv.w*xv.w;
#pragma unroll
    for (int off = 32; off; off >>= 1) {
        s  += __shfl_xor(s,  off, 64);
        ss += __shfl_xor(ss, off, 64);
    }
    float mu  = s * (1.0f / 256.0f);
    float inv = rsqrtf(ss * (1.0f / 256.0f) - mu * mu + 1e-5f);
    float4 gv = *(const float4*)(g + (lane << 2));
    float4 bv = *(const float4*)(b + (lane << 2));
    ushort4 o;
    o.x = f2bf((xv.x - mu) * inv * gv.x + bv.x);
    o.y = f2bf((xv.y - mu) * inv * gv.y + bv.y);
    o.z = f2bf((xv.z - mu) * inv * gv.z + bv.z);
    o.w = f2bf((xv.w - mu) * inv * gv.w + bv.w);
    *(ushort4*)(out + (size_t)row * 256 + (lane << 2)) = o;
}

// ---- prep: 4x weight transpose+bf16 convert, + rel-pos bias expand --------
__device__ __forceinline__ void convT_body(
    const float* __restrict__ in, unsigned short* __restrict__ out,
    int K, int N, int b, float (*t)[33], int tid)
{
    int kb = K >> 5;
    int bk = (b % kb) << 5;
    int bn = (b / kb) << 5;
    int r = tid >> 5, c = tid & 31;
#pragma unroll
    for (int i = 0; i < 4; ++i)
        t[r + i * 8][c] = in[(size_t)(bk + r + i * 8) * N + bn + c];
    __syncthreads();
#pragma unroll
    for (int i = 0; i < 4; ++i)
        out[(size_t)(bn + r + i * 8) * K + bk + c] = f2bf(t[c][r + i * 8]);
}

__global__ __launch_bounds__(256) void prep_kernel(
    const float* __restrict__ qkv_w, const float* __restrict__ proj_w,
    const float* __restrict__ w1, const float* __restrict__ w2,
    unsigned short* __restrict__ qkvT, unsigned short* __restrict__ prjT,
    unsigned short* __restrict__ w1T, unsigned short* __restrict__ w2T,
    const float* __restrict__ table, const int* __restrict__ relidx,
    float* __restrict__ bexp)
{
    __shared__ float t[32][33];
    const int b = blockIdx.x, tid = threadIdx.x;
    if      (b < 192) convT_body(qkv_w, qkvT, 256,  768, b,       t, tid);
    else if (b < 256) convT_body(proj_w, prjT, 256,  256, b - 192, t, tid);
    else if (b < 512) convT_body(w1,    w1T,  256, 1024, b - 256, t, tid);
    else if (b < 768) convT_body(w2,    w2T, 1024,  256, b - 512, t, tid);
    else {
        int i = (b - 768) * 256 + tid;       // 8*64*64 = 32768
        int head = i >> 12;
        int q = (i >> 6) & 63;
        int k = i & 63;
        bexp[i] = table[relidx[q * 64 + k] * 8 + head];
    }
}

// ---- MFMA GEMM: A bf16 [M,K] row-major, BT bf16 [N,K] row-major -----------
// 128x128 tile, 512 thr / 8 waves (wave = 32m x 64n, acc[4][2] C^T).
// Depth-4 ring prefetch, XCD swizzle, XOR-swizzled LDS.
// NEW: coalesced epilogue via LDS output-tile staging (reuses ring LDS).
template<int OUT_BF16, int DO_GELU, int RESID, int QSCALE, int RESBF>
__global__ __launch_bounds__(512, 2) void mgemm_kernel(
    const unsigned short* __restrict__ A, const unsigned short* __restrict__ BT,
    const float* __restrict__ bias, void* __restrict__ outp,
    const void* __restrict__ resid, int M, int N, int K)
{
    __shared__ __align__(16) unsigned short smem[32768];   // 64KB
#define ASB(b) (smem + (b) * 4096)
#define BSB(b) (smem + 16384 + (b) * 4096)

    const int cpx = (int)gridDim.x >> 3;
    const int bid = ((int)blockIdx.x & 7) * cpx + ((int)blockIdx.x >> 3);

    const int nb = N >> 7;
    const int m0 = (bid / nb) << 7;
    const int n0 = (bid % nb) << 7;
    const int tid  = threadIdx.x;
    const int wid  = tid >> 6;
    const int lane = tid & 63;
    const int wm = (wid >> 1) << 5;        // 0,32,64,96
    const int wn = (wid & 1) << 6;         // 0,64

    const unsigned short* Ag = A  + (size_t)m0 * K;
    const unsigned short* Bg = BT + (size_t)n0 * K;
    const size_t ra = (size_t)(tid >> 2) * K + (((tid & 3) ^ ((tid >> 2) & 3)) << 3);

    f32x4 acc[4][2] = {};          // acc[j][i] = C^T fragment (j: n, i: m)
    const int fr = lane & 15;
    const int fq = lane >> 4;
    const int axor = ((fq ^ (fr & 3)) << 3);

#define STAGE(buf, kk)                                                        \
    {                                                                         \
        gload16(Ag + ra + (kk), ASB(buf) + tid * 8);                          \
        gload16(Bg + ra + (kk), BSB(buf) + tid * 8);                          \
    }

    const int NIT = K >> 5;
    STAGE(0, 0);
    STAGE(1, 32);
    STAGE(2, 64);

    for (int t = 0; t < NIT; ++t) {
        if (t + 2 < NIT)      asm volatile("s_waitcnt vmcnt(4)" ::: "memory");
        else if (t + 1 < NIT) asm volatile("s_waitcnt vmcnt(2)" ::: "memory");
        else                  asm volatile("s_waitcnt vmcnt(0)" ::: "memory");
        __builtin_amdgcn_s_barrier();

        const int cur = t & 3;
        bf16x8 af[2], bfr[4];
#pragma unroll
        for (int i = 0; i < 2; ++i)
            af[i] = *(const bf16x8*)(ASB(cur) + (wm + i * 16 + fr) * 32 + axor);
#pragma unroll
        for (int j = 0; j < 4; ++j)
            bfr[j] = *(const bf16x8*)(BSB(cur) + (wn + j * 16 + fr) * 32 + axor);
#pragma unroll
        for (int j = 0; j < 4; ++j)
#pragma unroll
            for (int i = 0; i < 2; ++i)
                acc[j][i] = __builtin_amdgcn_mfma_f32_16x16x32_bf16(
                    bfr[j], af[i], acc[j][i], 0, 0, 0);   // C^T: operands swapped

        if (t + 3 < NIT) STAGE((t + 3) & 3, (t + 3) << 5);
    }
#undef STAGE

    // ---- epilogue: fragments -> LDS tile -> coalesced global stores --------
    __builtin_amdgcn_s_barrier();   // all K-loop LDS reads complete

#pragma unroll
    for (int j = 0; j < 4; ++j) {
        const int fc = wn + j * 16 + (fq << 2);      // tile-local col (mult of 4)
        const int gcol = n0 + fc;
        const float4 b4 = *(const float4*)(bias + gcol);
#pragma unroll
        for (int i = 0; i < 2; ++i) {
            const int row = wm + i * 16 + fr;        // tile-local row
            float v0 = acc[j][i][0] + b4.x;
            float v1 = acc[j][i][1] + b4.y;
            float v2 = acc[j][i][2] + b4.z;
            float v3 = acc[j][i][3] + b4.w;
            if (QSCALE && gcol < 256) {
                v0 *= 0.17677669529663687f; v1 *= 0.17677669529663687f;
                v2 *= 0.17677669529663687f; v3 *= 0.17677669529663687f;
            }
            if (DO_GELU) {
                v0 = gelu_f(v0); v1 = gelu_f(v1); v2 = gelu_f(v2); v3 = gelu_f(v3);
            }
            if (OUT_BF16) {
                // bf16 tile: 8B units, unit = row*32 + ((fc>>2) ^ (row&6))
                uint2 pp;
                pp.x = cvtpk_bf16(v0, v1);
                pp.y = cvtpk_bf16(v2, v3);
                const int u = (row << 5) + ((fc >> 2) ^ (row & 6));
                *(uint2*)((char*)smem + (size_t)u * 8) = pp;
            } else {
                // f32 tile: 16B units, unit = row*32 + ((fc>>2) ^ (row&7))
                float4 o4; o4.x = v0; o4.y = v1; o4.z = v2; o4.w = v3;
                const int u = (row << 5) + ((fc >> 2) ^ (row & 7));
                *(float4*)((char*)smem + (size_t)u * 16) = o4;
            }
        }
    }
    __builtin_amdgcn_s_barrier();

    if (OUT_BF16) {
        // readout: 4 passes, 16B (8 bf16) per thread, 256B/row per wave
#pragma unroll
        for (int p = 0; p < 4; ++p) {
            const int row = (p << 5) + (tid >> 4);
            const int q = tid & 15;
            const int u = (row << 5) + ((q << 1) ^ (row & 6));
            uint4 a = *(const uint4*)((const char*)smem + (size_t)u * 8);
            const int grow = m0 + row;
            const int orow = (RESID == 2) ? remap_row(grow) : grow;
            const int gcol = n0 + (q << 3);
            if (RESID) {
                float rv[8];
                if (RESBF) {
                    ushort4 ra_ = *(const ushort4*)((const unsigned short*)resid
                                                    + (size_t)orow * N + gcol);
                    ushort4 rb_ = *(const ushort4*)((const unsigned short*)resid
                                                    + (size_t)orow * N + gcol + 4);
                    rv[0]=bf2f(ra_.x); rv[1]=bf2f(ra_.y); rv[2]=bf2f(ra_.z); rv[3]=bf2f(ra_.w);
                    rv[4]=bf2f(rb_.x); rv[5]=bf2f(rb_.y); rv[6]=bf2f(rb_.z); rv[7]=bf2f(rb_.w);
                } else {
                    float4 ra_ = *(const float4*)((const float*)resid + (size_t)orow * N + gcol);
                    float4 rb_ = *(const float4*)((const float*)resid + (size_t)orow * N + gcol + 4);
                    rv[0]=ra_.x; rv[1]=ra_.y; rv[2]=ra_.z; rv[3]=ra_.w;
                    rv[4]=rb_.x; rv[5]=rb_.y; rv[6]=rb_.z; rv[7]=rb_.w;
                }
                const unsigned short* s = (const unsigned short*)&a;
                uint4 o;
                o.x = cvtpk_bf16(bf2f(s[0]) + rv[0], bf2f(s[1]) + rv[1]);
                o.y = cvtpk_bf16(bf2f(s[2]) + rv[2], bf2f(s[3]) + rv[3]);
                o.z = cvtpk_bf16(bf2f(s[4]) + rv[4], bf2f(s[5]) + rv[5]);
                o.w = cvtpk_bf16(bf2f(s[6]) + rv[6], bf2f(s[7]) + rv[7]);
                a = o;
            }
            *(uint4*)((unsigned short*)outp + (size_t)orow * N + gcol) = a;
        }
    } else {
        // readout: 8 passes, 16B (4 f32) per thread, 512B/row per wave
#pragma unroll
        for (int p = 0; p < 8; ++p) {
            const int row = (p << 4) + (tid >> 5);
            const int q = tid & 31;
            const int u = (row << 5) + (q ^ (row & 7));
            float4 v = *(const float4*)((const char*)smem + (size_t)u * 16);
            const int grow = m0 + row;
            const int orow = (RESID == 2) ? remap_row(grow) : grow;
            const int gcol = n0 + (q << 2);
            if (RESID) {
                if (RESBF) {
                    ushort4 r4 = *(const ushort4*)((const unsigned short*)resid
                                                   + (size_t)orow * N + gcol);
                    v.x += bf2f(r4.x); v.y += bf2f(r4.y);
                    v.z += bf2f(r4.z); v.w += bf2f(r4.w);
                } else {
                    float4 r4 = *(const float4*)((const float*)resid + (size_t)orow * N + gcol);
                    v.x += r4.x; v.y += r4.y; v.z += r4.z; v.w += r4.w;
                }
            }
            *(float4*)((float*)outp + (size_t)orow * N + gcol) = v;
        }
    }
#undef ASB
#undef BSB
}

// ---- MFMA window attention: one wave per (window, head) -------------------
__global__ __launch_bounds__(64, 3) void attn_kernel(
    const unsigned short* __restrict__ qkv,
    const float* __restrict__ bexp,
    unsigned short* __restrict__ out)
{
    __shared__ unsigned short VT[2048];
    const int bid  = blockIdx.x;
    const int widx = bid & 1023;
    const int head = bid >> 10;
    const int l  = threadIdx.x;
    const int lo = l & 31, hi = l >> 5;

    const unsigned short* base = qkv + (size_t)widx * 64 * 768;

#pragma unroll
    for (int c = 0; c < 4; ++c) {
        union { bf16x8 v; unsigned short s[8]; } u;
        u.v = *(const bf16x8*)(base + (size_t)l * 768 + 512 + head * 32 + c * 8);
#pragma unroll
        for (int e = 0; e < 8; ++e) {
            int d = c * 8 + e;
            int wb = ((d * 64 + l) * 2) ^ ((d & 7) << 4);
            *(unsigned short*)((char*)VT + wb) = u.s[e];
        }
    }

    f32x16 acc[2][2] = {};
#pragma unroll
    for (int kd = 0; kd < 2; ++kd) {
        const int coff = head * 32 + kd * 16 + hi * 8;
        bf16x8 kf0 = *(const bf16x8*)(base + (size_t)lo        * 768 + 256 + coff);
        bf16x8 kf1 = *(const bf16x8*)(base + (size_t)(32 + lo) * 768 + 256 + coff);
        bf16x8 qf0 = *(const bf16x8*)(base + (size_t)lo        * 768 + coff);
        bf16x8 qf1 = *(const bf16x8*)(base + (size_t)(32 + lo) * 768 + coff);
        acc[0][0] = __builtin_amdgcn_mfma_f32_32x32x16_bf16(kf0, qf0, acc[0][0], 0, 0, 0);
        acc[0][1] = __builtin_amdgcn_mfma_f32_32x32x16_bf16(kf0, qf1, acc[0][1], 0, 0, 0);
        acc[1][0] = __builtin_amdgcn_mfma_f32_32x32x16_bf16(kf1, qf0, acc[1][0], 0, 0, 0);
        acc[1][1] = __builtin_amdgcn_mfma_f32_32x32x16_bf16(kf1, qf1, acc[1][1], 0, 0, 0);
    }

#pragma unroll
    for (int qb = 0; qb < 2; ++qb) {
        const float* bq = bexp + head * 4096 + (qb * 32 + lo) * 64;
#pragma unroll
        for (int kb = 0; kb < 2; ++kb)
#pragma unroll
            for (int j = 0; j < 4; ++j) {
                float4 b4 = *(const float4*)(bq + kb * 32 + j * 8 + hi * 4);
                acc[kb][qb][4 * j + 0] += b4.x;
                acc[kb][qb][4 * j + 1] += b4.y;
                acc[kb][qb][4 * j + 2] += b4.z;
                acc[kb][qb][4 * j + 3] += b4.w;
            }
    }

    const int w6 = widx & 63;
    if (((w6 >> 3) == 7) || ((w6 & 7) == 7)) {
#pragma unroll
        for (int qb = 0; qb < 2; ++qb) {
            int nq = qb * 32 + lo;
            int phq = ((w6 >> 3) << 3) + (nq >> 3), pwq = ((w6 & 7) << 3) + (nq & 7);
            int rq = ((phq < 56) ? 0 : ((phq < 60) ? 1 : 2)) * 3
                   + ((pwq < 56) ? 0 : ((pwq < 60) ? 1 : 2));
#pragma unroll
            for (int kb = 0; kb < 2; ++kb)
#pragma unroll
                for (int r = 0; r < 16; ++r) {
                    int nk = kb * 32 + (r & 3) + 8 * (r >> 2) + 4 * hi;
                    int phk = ((w6 >> 3) << 3) + (nk >> 3), pwk = ((w6 & 7) << 3) + (nk & 7);
                    int rk = ((phk < 56) ? 0 : ((phk < 60) ? 1 : 2)) * 3
                           + ((pwk < 56) ? 0 : ((pwk < 60) ? 1 : 2));
                    if (rk != rq) acc[kb][qb][r] -= 100.0f;
                }
        }
    }

#pragma unroll
    for (int qb = 0; qb < 2; ++qb) {
        float mx = acc[0][qb][0];
#pragma unroll
        for (int r = 1; r < 16; ++r) mx = fmaxf(mx, acc[0][qb][r]);
#pragma unroll
        for (int r = 0; r < 16; ++r) mx = fmaxf(mx, acc[1][qb][r]);
        mx = fmaxf(mx, __shfl_xor(mx, 32, 64));
        float sum = 0.f;
#pragma unroll
        for (int kb = 0; kb < 2; ++kb)
#pragma unroll
            for (int r = 0; r < 16; ++r) {
                float e = __expf(acc[kb][qb][r] - mx);
                acc[kb][qb][r] = e;
                sum += e;
            }
        sum += __shfl_xor(sum, 32, 64);
        float inv = 1.0f / sum;
#pragma unroll
        for (int kb = 0; kb < 2; ++kb)
#pragma unroll
            for (int r = 0; r < 16; ++r) acc[kb][qb][r] *= inv;
    }

    f32x16 o[2] = {};
#pragma unroll
    for (int ks = 0; ks < 4; ++ks) {
        const int s8 = (ks & 1) * 8, kb = ks >> 1;
        const int rb = ((lo * 64 + 16 * ks + 8 * hi) * 2) ^ ((lo & 7) << 4);
        bf16x8 vb = *(const bf16x8*)((const char*)VT + rb);
#pragma unroll
        for (int qb = 0; qb < 2; ++qb) {
            unsigned int a0 = cvtpk_bf16(acc[kb][qb][s8 + 0], acc[kb][qb][s8 + 1]);
            unsigned int b0 = cvtpk_bf16(acc[kb][qb][s8 + 4], acc[kb][qb][s8 + 5]);
            unsigned int a1 = cvtpk_bf16(acc[kb][qb][s8 + 2], acc[kb][qb][s8 + 3]);
            unsigned int b1 = cvtpk_bf16(acc[kb][qb][s8 + 6], acc[kb][qb][s8 + 7]);
            perm32swap(a0, b0);
            perm32swap(a1, b1);
            union { unsigned int u[4]; bf16x8 v; } w;
            w.u[0] = a0; w.u[1] = a1; w.u[2] = b0; w.u[3] = b1;
            o[qb] = __builtin_amdgcn_mfma_f32_32x32x16_bf16(w.v, vb, o[qb], 0, 0, 0);
        }
    }

    unsigned short* ob = out + (size_t)widx * 64 * 256 + head * 32 + lo;
#pragma unroll
    for (int qb = 0; qb < 2; ++qb)
#pragma unroll
        for (int r = 0; r < 16; ++r) {
            int q = qb * 32 + (r & 3) + 8 * (r >> 2) + 4 * hi;
            ob[(size_t)q * 256] = f2bf(o[qb][r]);
        }
}

// ---------------------------------------------------------------------------
extern "C" void kernel_launch(void* const* d_in, const int* in_sizes, int n_in,
                              void* d_out, int out_size, void* d_ws, size_t ws_size,
                              hipStream_t stream)
{
    const float* x      = (const float*)d_in[0];
    const float* ln1_g  = (const float*)d_in[1];
    const float* ln1_b  = (const float*)d_in[2];
    const float* qkv_w  = (const float*)d_in[3];
    const float* qkv_b  = (const float*)d_in[4];
    const float* proj_w = (const float*)d_in[5];
    const float* proj_b = (const float*)d_in[6];
    const float* table  = (const float*)d_in[7];
    const float* ln2_g  = (const float*)d_in[8];
    const float* ln2_b  = (const float*)d_in[9];
    const float* w1     = (const float*)d_in[10];
    const float* b1     = (const float*)d_in[11];
    const float* w2     = (const float*)d_in[12];
    const float* b2     = (const float*)d_in[13];
    const int*   relidx = (const int*)d_in[14];
    float* out = (float*)d_out;

    char* w = (char*)d_ws;
    unsigned short* xw   = (unsigned short*)w;                      // 32MB (xw -> attn_out -> ln2out)
    unsigned short* qkvb = (unsigned short*)(w + (32u << 20));      // 128MB (qkv 96MB -> mlp hidden 128MB)
    unsigned short* h2b  = (unsigned short*)(w + (160u << 20));     // 32MB (bf16 residual stream)
    float*          bexp = (float*)(w + (224u << 20));              // 128KB
    unsigned short* qkvT = (unsigned short*)(w + (224u << 20) + (128u << 10)); // 384KB
    unsigned short* prjT = qkvT + 768 * 256;                        // 128KB
    unsigned short* w1T  = prjT + 256 * 256;                        // 512KB
    unsigned short* w2T  = w1T + 1024 * 256;                        // 512KB

    // 0. weight transposes + bf16 convert + rel-pos bias expand (one kernel)
    prep_kernel<<<896, 256, 0, stream>>>(qkv_w, proj_w, w1, w2,
                                         qkvT, prjT, w1T, w2T,
                                         table, relidx, bexp);
    // 1. LN1 + cyclic shift + window partition (gather) -> xw bf16 [65536,256]
    ln_kernel<0><<<16384, 256, 0, stream>>>(x, ln1_g, ln1_b, xw, 1);
    // 2. QKV GEMM (q cols pre-scaled by hd^-0.5) -> qkvb bf16 [65536,768]
    mgemm_kernel<1, 0, 0, 1, 0><<<512 * 6, 512, 0, stream>>>(
        xw, qkvT, qkv_b, (void*)qkvb, nullptr, 65536, 768, 256);
    // 3. MFMA window attention -> attn_out (reuse xw) bf16 [65536,256]
    attn_kernel<<<8192, 64, 0, stream>>>(qkvb, bexp, xw);
    // 4. proj GEMM + window-reverse/unshift scatter + residual(x f32) -> h2b bf16
    mgemm_kernel<1, 0, 2, 0, 0><<<512 * 2, 512, 0, stream>>>(
        xw, prjT, proj_b, (void*)h2b, x, 65536, 256, 256);
    // 5. LN2 (bf16 in) -> ln2out (reuse xw) bf16
    ln_kernel<1><<<16384, 256, 0, stream>>>(h2b, ln2_g, ln2_b, xw, 0);
    // 6. MLP1 GEMM + GELU -> hidden (reuse qkvb) bf16 [65536,1024]
    mgemm_kernel<1, 1, 0, 0, 0><<<512 * 8, 512, 0, stream>>>(
        xw, w1T, b1, (void*)qkvb, nullptr, 65536, 1024, 256);
    // 7. MLP2 GEMM + residual(h2b bf16) -> d_out f32
    mgemm_kernel<0, 0, 1, 0, 1><<<512 * 2, 512, 0, stream>>>(
        qkvb, w2T, b2, (void*)out, h2b, 65536, 256, 1024);
}

// Round 15
// 282.714 us; speedup vs baseline: 1.0346x; 1.0346x over previous
//
#include <hip/hip_runtime.h>

// ---------------------------------------------------------------------------
// Swin block: LN1 -> [fused QKV + win-attn] -> proj+resid -> LN2 -> MLP1(GELU)
//             -> MLP2 + residual
// B=16 H=W=64 C=256 WS=8 SHIFT=4 HEADS=8 HD=32 N=64 HID=1024
// Round 15: QKV GEMM + attention FUSED (one block per window, wave=head):
//           A-tile 64x256 in LDS once; K/Q/V computed per-wave with
//           register-direct L2-resident weights; acc->operand conversion via
//           the verified cvt_pk+permlane32_swap dance; S/softmax/PV unchanged.
//           Kills the 96MB qkv write + 96MB read. Attn out staged via LDS
//           for coalesced 16B stores.
// ---------------------------------------------------------------------------

typedef __attribute__((ext_vector_type(8))) short bf16x8;
typedef __attribute__((ext_vector_type(4))) float f32x4;
typedef __attribute__((ext_vector_type(16))) float f32x16;

__device__ __forceinline__ float bf2f(unsigned short h) {
    union { unsigned int u; float f; } c; c.u = ((unsigned int)h) << 16; return c.f;
}
__device__ __forceinline__ unsigned short f2bf(float f) {
    union { float f; unsigned int u; } c; c.f = f;
    unsigned int u = c.u;
    return (unsigned short)((u + 0x7FFFu + ((u >> 16) & 1u)) >> 16);
}
__device__ __forceinline__ unsigned int cvtpk_bf16(float lo, float hi) {
    unsigned int r;
    asm volatile("v_cvt_pk_bf16_f32 %0, %1, %2" : "=v"(r) : "v"(lo), "v"(hi));
    return r;
}
__device__ __forceinline__ void perm32swap(unsigned int& a, unsigned int& b) {
    asm volatile("v_permlane32_swap_b32 %0, %1" : "+v"(a), "+v"(b));
}
// window-order row (b, wi, wj, r, cc) -> pixel-order row (b, hp, wp).
__device__ __forceinline__ int remap_row(int row) {
    int b  = row >> 12;
    int w6 = (row >> 6) & 63;
    int n  = row & 63;
    int hp = (((w6 >> 3) << 3) + (n >> 3) + 4) & 63;
    int wp = (((w6 & 7) << 3) + (n & 7) + 4) & 63;
    return (b << 12) | (hp << 6) | wp;
}
// gelu(v) = v * sigmoid(2c(v + 0.044715 v^3)), c = sqrt(2/pi)
__device__ __forceinline__ float gelu_f(float v) {
    float u = 1.5957691216057308f * (v + 0.044715f * v * v * v);
    return v / (1.0f + __expf(-u));
}
__device__ __forceinline__ void gload16(const unsigned short* g, unsigned short* l) {
    __builtin_amdgcn_global_load_lds(
        (const __attribute__((address_space(1))) void*)g,
        (__attribute__((address_space(3))) void*)l, 16, 0, 0);
}

// ---- LayerNorm over C=256; one wave per row; optional gather remap --------
template<int INBF>
__global__ __launch_bounds__(256) void ln_kernel(
    const void* __restrict__ inp, const float* __restrict__ g,
    const float* __restrict__ b, unsigned short* __restrict__ out, int remap)
{
    int wave = threadIdx.x >> 6, lane = threadIdx.x & 63;
    int row = (blockIdx.x << 2) + wave;
    int src = remap ? remap_row(row) : row;
    float4 xv;
    if (INBF) {
        ushort4 u = *(const ushort4*)((const unsigned short*)inp + (size_t)src * 256 + (lane << 2));
        xv.x = bf2f(u.x); xv.y = bf2f(u.y); xv.z = bf2f(u.z); xv.w = bf2f(u.w);
    } else {
        xv = *(const float4*)((const float*)inp + (size_t)src * 256 + (lane << 2));
    }
    float s  = xv.x + xv.y + xv.z + xv.w;
    float ss = xv.x*xv.x + xv.y*xv.y + xv.z*xv.z + xv.w*xv.w;
#pragma unroll
    for (int off = 32; off; off >>= 1) {
        s  += __shfl_xor(s,  off, 64);
        ss += __shfl_xor(ss, off, 64);
    }
    float mu  = s * (1.0f / 256.0f);
    float inv = rsqrtf(ss * (1.0f / 256.0f) - mu * mu + 1e-5f);
    float4 gv = *(const float4*)(g + (lane << 2));
    float4 bv = *(const float4*)(b + (lane << 2));
    ushort4 o;
    o.x = f2bf((xv.x - mu) * inv * gv.x + bv.x);
    o.y = f2bf((xv.y - mu) * inv * gv.y + bv.y);
    o.z = f2bf((xv.z - mu) * inv * gv.z + bv.z);
    o.w = f2bf((xv.w - mu) * inv * gv.w + bv.w);
    *(ushort4*)(out + (size_t)row * 256 + (lane << 2)) = o;
}

// ---- prep: 4x weight transpose+bf16 convert, + rel-pos bias expand --------
__device__ __forceinline__ void convT_body(
    const float* __restrict__ in, unsigned short* __restrict__ out,
    int K, int N, int b, float (*t)[33], int tid)
{
    int kb = K >> 5;
    int bk = (b % kb) << 5;
    int bn = (b / kb) << 5;
    int r = tid >> 5, c = tid & 31;
#pragma unroll
    for (int i = 0; i < 4; ++i)
        t[r + i * 8][c] = in[(size_t)(bk + r + i * 8) * N + bn + c];
    __syncthreads();
#pragma unroll
    for (int i = 0; i < 4; ++i)
        out[(size_t)(bn + r + i * 8) * K + bk + c] = f2bf(t[c][r + i * 8]);
}

__global__ __launch_bounds__(256) void prep_kernel(
    const float* __restrict__ qkv_w, const float* __restrict__ proj_w,
    const float* __restrict__ w1, const float* __restrict__ w2,
    unsigned short* __restrict__ qkvT, unsigned short* __restrict__ prjT,
    unsigned short* __restrict__ w1T, unsigned short* __restrict__ w2T,
    const float* __restrict__ table, const int* __restrict__ relidx,
    float* __restrict__ bexp)
{
    __shared__ float t[32][33];
    const int b = blockIdx.x, tid = threadIdx.x;
    if      (b < 192) convT_body(qkv_w, qkvT, 256,  768, b,       t, tid);
    else if (b < 256) convT_body(proj_w, prjT, 256,  256, b - 192, t, tid);
    else if (b < 512) convT_body(w1,    w1T,  256, 1024, b - 256, t, tid);
    else if (b < 768) convT_body(w2,    w2T, 1024,  256, b - 512, t, tid);
    else {
        int i = (b - 768) * 256 + tid;       // 8*64*64 = 32768
        int head = i >> 12;
        int q = (i >> 6) & 63;
        int k = i & 63;
        bexp[i] = table[relidx[q * 64 + k] * 8 + head];
    }
}

// ---- MFMA GEMM (proj / MLP1 / MLP2): as R12 -------------------------------
template<int OUT_BF16, int DO_GELU, int RESID, int QSCALE, int RESBF>
__global__ __launch_bounds__(512, 2) void mgemm_kernel(
    const unsigned short* __restrict__ A, const unsigned short* __restrict__ BT,
    const float* __restrict__ bias, void* __restrict__ outp,
    const void* __restrict__ resid, int M, int N, int K)
{
    __shared__ __align__(16) unsigned short smem[32768];   // 64KB
#define ASB(b) (smem + (b) * 4096)
#define BSB(b) (smem + 16384 + (b) * 4096)

    const int cpx = (int)gridDim.x >> 3;
    const int bid = ((int)blockIdx.x & 7) * cpx + ((int)blockIdx.x >> 3);

    const int nb = N >> 7;
    const int m0 = (bid / nb) << 7;
    const int n0 = (bid % nb) << 7;
    const int tid  = threadIdx.x;
    const int wid  = tid >> 6;
    const int lane = tid & 63;
    const int wm = (wid >> 1) << 5;
    const int wn = (wid & 1) << 6;

    const unsigned short* Ag = A  + (size_t)m0 * K;
    const unsigned short* Bg = BT + (size_t)n0 * K;
    const size_t ra = (size_t)(tid >> 2) * K + (((tid & 3) ^ ((tid >> 2) & 3)) << 3);

    f32x4 acc[4][2] = {};
    const int fr = lane & 15;
    const int fq = lane >> 4;
    const int axor = ((fq ^ (fr & 3)) << 3);

#define STAGE(buf, kk)                                                        \
    {                                                                         \
        gload16(Ag + ra + (kk), ASB(buf) + tid * 8);                          \
        gload16(Bg + ra + (kk), BSB(buf) + tid * 8);                          \
    }

    const int NIT = K >> 5;
    STAGE(0, 0);
    STAGE(1, 32);
    STAGE(2, 64);

    for (int t = 0; t < NIT; ++t) {
        if (t + 2 < NIT)      asm volatile("s_waitcnt vmcnt(4)" ::: "memory");
        else if (t + 1 < NIT) asm volatile("s_waitcnt vmcnt(2)" ::: "memory");
        else                  asm volatile("s_waitcnt vmcnt(0)" ::: "memory");
        __builtin_amdgcn_s_barrier();

        const int cur = t & 3;
        bf16x8 af[2], bfr[4];
#pragma unroll
        for (int i = 0; i < 2; ++i)
            af[i] = *(const bf16x8*)(ASB(cur) + (wm + i * 16 + fr) * 32 + axor);
#pragma unroll
        for (int j = 0; j < 4; ++j)
            bfr[j] = *(const bf16x8*)(BSB(cur) + (wn + j * 16 + fr) * 32 + axor);
#pragma unroll
        for (int j = 0; j < 4; ++j)
#pragma unroll
            for (int i = 0; i < 2; ++i)
                acc[j][i] = __builtin_amdgcn_mfma_f32_16x16x32_bf16(
                    bfr[j], af[i], acc[j][i], 0, 0, 0);   // C^T

        if (t + 3 < NIT) STAGE((t + 3) & 3, (t + 3) << 5);
    }
#undef STAGE

    __builtin_amdgcn_s_barrier();

#pragma unroll
    for (int j = 0; j < 4; ++j) {
        const int fc = wn + j * 16 + (fq << 2);
        const int gcol = n0 + fc;
        const float4 b4 = *(const float4*)(bias + gcol);
#pragma unroll
        for (int i = 0; i < 2; ++i) {
            const int row = wm + i * 16 + fr;
            float v0 = acc[j][i][0] + b4.x;
            float v1 = acc[j][i][1] + b4.y;
            float v2 = acc[j][i][2] + b4.z;
            float v3 = acc[j][i][3] + b4.w;
            if (QSCALE && gcol < 256) {
                v0 *= 0.17677669529663687f; v1 *= 0.17677669529663687f;
                v2 *= 0.17677669529663687f; v3 *= 0.17677669529663687f;
            }
            if (DO_GELU) {
                v0 = gelu_f(v0); v1 = gelu_f(v1); v2 = gelu_f(v2); v3 = gelu_f(v3);
            }
            if (OUT_BF16) {
                uint2 pp;
                pp.x = cvtpk_bf16(v0, v1);
                pp.y = cvtpk_bf16(v2, v3);
                const int u = (row << 5) + ((fc >> 2) ^ (row & 6));
                *(uint2*)((char*)smem + (size_t)u * 8) = pp;
            } else {
                float4 o4; o4.x = v0; o4.y = v1; o4.z = v2; o4.w = v3;
                const int u = (row << 5) + ((fc >> 2) ^ (row & 7));
                *(float4*)((char*)smem + (size_t)u * 16) = o4;
            }
        }
    }
    __builtin_amdgcn_s_barrier();

    if (OUT_BF16) {
#pragma unroll
        for (int p = 0; p < 4; ++p) {
            const int row = (p << 5) + (tid >> 4);
            const int q = tid & 15;
            const int u = (row << 5) + ((q << 1) ^ (row & 6));
            uint4 a = *(const uint4*)((const char*)smem + (size_t)u * 8);
            const int grow = m0 + row;
            const int orow = (RESID == 2) ? remap_row(grow) : grow;
            const int gcol = n0 + (q << 3);
            if (RESID) {
                float rv[8];
                if (RESBF) {
                    ushort4 ra_ = *(const ushort4*)((const unsigned short*)resid
                                                    + (size_t)orow * N + gcol);
                    ushort4 rb_ = *(const ushort4*)((const unsigned short*)resid
                                                    + (size_t)orow * N + gcol + 4);
                    rv[0]=bf2f(ra_.x); rv[1]=bf2f(ra_.y); rv[2]=bf2f(ra_.z); rv[3]=bf2f(ra_.w);
                    rv[4]=bf2f(rb_.x); rv[5]=bf2f(rb_.y); rv[6]=bf2f(rb_.z); rv[7]=bf2f(rb_.w);
                } else {
                    float4 ra_ = *(const float4*)((const float*)resid + (size_t)orow * N + gcol);
                    float4 rb_ = *(const float4*)((const float*)resid + (size_t)orow * N + gcol + 4);
                    rv[0]=ra_.x; rv[1]=ra_.y; rv[2]=ra_.z; rv[3]=ra_.w;
                    rv[4]=rb_.x; rv[5]=rb_.y; rv[6]=rb_.z; rv[7]=rb_.w;
                }
                const unsigned short* s = (const unsigned short*)&a;
                uint4 o;
                o.x = cvtpk_bf16(bf2f(s[0]) + rv[0], bf2f(s[1]) + rv[1]);
                o.y = cvtpk_bf16(bf2f(s[2]) + rv[2], bf2f(s[3]) + rv[3]);
                o.z = cvtpk_bf16(bf2f(s[4]) + rv[4], bf2f(s[5]) + rv[5]);
                o.w = cvtpk_bf16(bf2f(s[6]) + rv[6], bf2f(s[7]) + rv[7]);
                a = o;
            }
            *(uint4*)((unsigned short*)outp + (size_t)orow * N + gcol) = a;
        }
    } else {
#pragma unroll
        for (int p = 0; p < 8; ++p) {
            const int row = (p << 4) + (tid >> 5);
            const int q = tid & 31;
            const int u = (row << 5) + (q ^ (row & 7));
            float4 v = *(const float4*)((const char*)smem + (size_t)u * 16);
            const int grow = m0 + row;
            const int orow = (RESID == 2) ? remap_row(grow) : grow;
            const int gcol = n0 + (q << 2);
            if (RESID) {
                if (RESBF) {
                    ushort4 r4 = *(const ushort4*)((const unsigned short*)resid
                                                   + (size_t)orow * N + gcol);
                    v.x += bf2f(r4.x); v.y += bf2f(r4.y);
                    v.z += bf2f(r4.z); v.w += bf2f(r4.w);
                } else {
                    float4 r4 = *(const float4*)((const float*)resid + (size_t)orow * N + gcol);
                    v.x += r4.x; v.y += r4.y; v.z += r4.z; v.w += r4.w;
                }
            }
            *(float4*)((float*)outp + (size_t)orow * N + gcol) = v;
        }
    }
#undef ASB
#undef BSB
}

// ---- fused QKV + window attention: one block per window, wave = head ------
// A-tile (ln1out window rows) 64x256 bf16 in 32KB LDS. Per wave: K/Q/V via
// 32x32x16 MFMA with register-direct weights; acc->operand via cvt_pk+
// permlane32_swap dance; S/softmax/PV as the verified attn path; O staged
// through LDS for coalesced 16B stores.
__global__ __launch_bounds__(512, 2) void qkvattn_kernel(
    const unsigned short* __restrict__ xw,    // bf16 [65536,256] window-ordered
    const unsigned short* __restrict__ qkvT,  // bf16 [768][256]
    const float* __restrict__ qkv_b,          // [768]
    const float* __restrict__ bexp,           // [8][64][64]
    unsigned short* __restrict__ out)         // bf16 [65536,256]
{
    __shared__ __align__(16) unsigned short Asm[16384];   // 32KB
    const int widx = blockIdx.x;
    const int tid  = threadIdx.x;
    const int head = tid >> 6;
    const int l    = tid & 63;
    const int lo   = l & 31, hi = l >> 5;

    // ---- stage A-tile: unit u holds row u>>5, logical grp (p&24)|((p^row)&7)
    {
        const unsigned short* Ag = xw + ((size_t)widx << 6) * 256;
#pragma unroll
        for (int i = 0; i < 4; ++i) {
            int u = tid + (i << 9);
            int r = u >> 5, p = u & 31;
            int lg = (p & 24) | ((p ^ r) & 7);
            gload16(Ag + (size_t)r * 256 + lg * 8, Asm + u * 8);
        }
        asm volatile("s_waitcnt vmcnt(0)" ::: "memory");
        __builtin_amdgcn_s_barrier();
    }

#define AREAD(tok, kk)                                                         \
    (*(const bf16x8*)(Asm + (tok) * 256 +                                      \
        (((((kk) >> 3) + hi) & 24) | (((((kk) >> 3) + hi) ^ (tok)) & 7)) * 8))

    // dance: acc (col=lane&31, row=(r&3)+8*(r>>2)+4*hi) -> op[kd]:
    // rows kd*16 + 8*hi + 0..7 as bf16x8 operand (verified P-frag pattern)
#define DANCE(aa, op0, op1)                                                    \
    {                                                                          \
        _Pragma("unroll")                                                      \
        for (int kd_ = 0; kd_ < 2; ++kd_) {                                    \
            const int s8_ = kd_ * 8;                                           \
            unsigned int a0 = cvtpk_bf16((aa)[s8_ + 0], (aa)[s8_ + 1]);        \
            unsigned int b0 = cvtpk_bf16((aa)[s8_ + 4], (aa)[s8_ + 5]);        \
            unsigned int a1 = cvtpk_bf16((aa)[s8_ + 2], (aa)[s8_ + 3]);        \
            unsigned int b1 = cvtpk_bf16((aa)[s8_ + 6], (aa)[s8_ + 7]);        \
            perm32swap(a0, b0);                                                \
            perm32swap(a1, b1);                                                \
            union { unsigned int u[4]; bf16x8 v; } w_;                         \
            w_.u[0] = a0; w_.u[1] = a1; w_.u[2] = b0; w_.u[3] = b1;            \
            if (kd_) (op1) = w_.v; else (op0) = w_.v;                          \
        }                                                                      \
    }

    bf16x8 opK[2][2], opQ[2][2];

    // ---- K then Q: acc = mfma(W-frag, A-frag): C[m=dim][n=token] ------------
#pragma unroll
    for (int mat = 0; mat < 2; ++mat) {
        const int sec = mat ? 0 : 1;            // K first (sec 1), then Q (sec 0)
        const unsigned short* Wb = qkvT + ((size_t)(sec * 256 + head * 32 + lo)) * 256 + 8 * hi;
        f32x16 ac[2] = {};
#pragma unroll
        for (int kk = 0; kk < 256; kk += 16) {
            bf16x8 wf = *(const bf16x8*)(Wb + kk);
#pragma unroll
            for (int tb = 0; tb < 2; ++tb)
                ac[tb] = __builtin_amdgcn_mfma_f32_32x32x16_bf16(
                    wf, AREAD(lo + 32 * tb, kk), ac[tb], 0, 0, 0);
        }
        const float* bb = qkv_b + sec * 256 + head * 32 + 4 * hi;
#pragma unroll
        for (int tb = 0; tb < 2; ++tb) {
#pragma unroll
            for (int qd = 0; qd < 4; ++qd) {
                float4 b4 = *(const float4*)(bb + 8 * qd);
                ac[tb][4 * qd + 0] += b4.x;
                ac[tb][4 * qd + 1] += b4.y;
                ac[tb][4 * qd + 2] += b4.z;
                ac[tb][4 * qd + 3] += b4.w;
                if (sec == 0) {
                    ac[tb][4 * qd + 0] *= 0.17677669529663687f;
                    ac[tb][4 * qd + 1] *= 0.17677669529663687f;
                    ac[tb][4 * qd + 2] *= 0.17677669529663687f;
                    ac[tb][4 * qd + 3] *= 0.17677669529663687f;
                }
            }
            if (sec == 1) { DANCE(ac[tb], opK[tb][0], opK[tb][1]); }
            else          { DANCE(ac[tb], opQ[tb][0], opQ[tb][1]); }
        }
    }

    // ---- S^T = K·Q^T (+bias, mask, softmax) — verified attn path -----------
    f32x16 acc[2][2] = {};   // [kb][qb]
#pragma unroll
    for (int kd = 0; kd < 2; ++kd) {
        acc[0][0] = __builtin_amdgcn_mfma_f32_32x32x16_bf16(opK[0][kd], opQ[0][kd], acc[0][0], 0, 0, 0);
        acc[0][1] = __builtin_amdgcn_mfma_f32_32x32x16_bf16(opK[0][kd], opQ[1][kd], acc[0][1], 0, 0, 0);
        acc[1][0] = __builtin_amdgcn_mfma_f32_32x32x16_bf16(opK[1][kd], opQ[0][kd], acc[1][0], 0, 0, 0);
        acc[1][1] = __builtin_amdgcn_mfma_f32_32x32x16_bf16(opK[1][kd], opQ[1][kd], acc[1][1], 0, 0, 0);
    }

#pragma unroll
    for (int qb = 0; qb < 2; ++qb) {
        const float* bq = bexp + head * 4096 + (qb * 32 + lo) * 64;
#pragma unroll
        for (int kb = 0; kb < 2; ++kb)
#pragma unroll
            for (int j = 0; j < 4; ++j) {
                float4 b4 = *(const float4*)(bq + kb * 32 + j * 8 + hi * 4);
                acc[kb][qb][4 * j + 0] += b4.x;
                acc[kb][qb][4 * j + 1] += b4.y;
                acc[kb][qb][4 * j + 2] += b4.z;
                acc[kb][qb][4 * j + 3] += b4.w;
            }
    }

    const int w6 = widx & 63;
    if (((w6 >> 3) == 7) || ((w6 & 7) == 7)) {
#pragma unroll
        for (int qb = 0; qb < 2; ++qb) {
            int nq = qb * 32 + lo;
            int phq = ((w6 >> 3) << 3) + (nq >> 3), pwq = ((w6 & 7) << 3) + (nq & 7);
            int rq = ((phq < 56) ? 0 : ((phq < 60) ? 1 : 2)) * 3
                   + ((pwq < 56) ? 0 : ((pwq < 60) ? 1 : 2));
#pragma unroll
            for (int kb = 0; kb < 2; ++kb)
#pragma unroll
                for (int r = 0; r < 16; ++r) {
                    int nk = kb * 32 + (r & 3) + 8 * (r >> 2) + 4 * hi;
                    int phk = ((w6 >> 3) << 3) + (nk >> 3), pwk = ((w6 & 7) << 3) + (nk & 7);
                    int rk = ((phk < 56) ? 0 : ((phk < 60) ? 1 : 2)) * 3
                           + ((pwk < 56) ? 0 : ((pwk < 60) ? 1 : 2));
                    if (rk != rq) acc[kb][qb][r] -= 100.0f;
                }
        }
    }

#pragma unroll
    for (int qb = 0; qb < 2; ++qb) {
        float mx = acc[0][qb][0];
#pragma unroll
        for (int r = 1; r < 16; ++r) mx = fmaxf(mx, acc[0][qb][r]);
#pragma unroll
        for (int r = 0; r < 16; ++r) mx = fmaxf(mx, acc[1][qb][r]);
        mx = fmaxf(mx, __shfl_xor(mx, 32, 64));
        float sum = 0.f;
#pragma unroll
        for (int kb = 0; kb < 2; ++kb)
#pragma unroll
            for (int r = 0; r < 16; ++r) {
                float e = __expf(acc[kb][qb][r] - mx);
                acc[kb][qb][r] = e;
                sum += e;
            }
        sum += __shfl_xor(sum, 32, 64);
        float inv = 1.0f / sum;
#pragma unroll
        for (int kb = 0; kb < 2; ++kb)
#pragma unroll
            for (int r = 0; r < 16; ++r) acc[kb][qb][r] *= inv;
    }

    // ---- V: acc = mfma(A-frag, W-frag): C[m=token][n=dim]; dance -> B-frags -
    bf16x8 vop[2][2];
    {
        const unsigned short* Wb = qkvT + ((size_t)(512 + head * 32 + lo)) * 256 + 8 * hi;
        f32x16 av[2] = {};
#pragma unroll
        for (int kk = 0; kk < 256; kk += 16) {
            bf16x8 wf = *(const bf16x8*)(Wb + kk);
#pragma unroll
            for (int tb = 0; tb < 2; ++tb)
                av[tb] = __builtin_amdgcn_mfma_f32_32x32x16_bf16(
                    AREAD(lo + 32 * tb, kk), wf, av[tb], 0, 0, 0);
        }
        const float bv = qkv_b[512 + head * 32 + lo];   // per-dim (col=lane)
#pragma unroll
        for (int tb = 0; tb < 2; ++tb) {
#pragma unroll
            for (int r = 0; r < 16; ++r) av[tb][r] += bv;
            DANCE(av[tb], vop[tb][0], vop[tb][1]);
        }
    }

    // ---- O = P·V (P-dance verbatim) ----------------------------------------
    f32x16 o[2] = {};
#pragma unroll
    for (int ks = 0; ks < 4; ++ks) {
        const int s8 = (ks & 1) * 8, kb = ks >> 1;
        bf16x8 vb = vop[ks >> 1][ks & 1];
#pragma unroll
        for (int qb = 0; qb < 2; ++qb) {
            unsigned int a0 = cvtpk_bf16(acc[kb][qb][s8 + 0], acc[kb][qb][s8 + 1]);
            unsigned int b0 = cvtpk_bf16(acc[kb][qb][s8 + 4], acc[kb][qb][s8 + 5]);
            unsigned int a1 = cvtpk_bf16(acc[kb][qb][s8 + 2], acc[kb][qb][s8 + 3]);
            unsigned int b1 = cvtpk_bf16(acc[kb][qb][s8 + 6], acc[kb][qb][s8 + 7]);
            perm32swap(a0, b0);
            perm32swap(a1, b1);
            union { unsigned int u[4]; bf16x8 v; } w;
            w.u[0] = a0; w.u[1] = a1; w.u[2] = b0; w.u[3] = b1;
            o[qb] = __builtin_amdgcn_mfma_f32_32x32x16_bf16(w.v, vb, o[qb], 0, 0, 0);
        }
    }

    // ---- O -> LDS -> coalesced 16B stores ----------------------------------
    __builtin_amdgcn_s_barrier();   // all waves done reading A-tile
#pragma unroll
    for (int qb = 0; qb < 2; ++qb)
#pragma unroll
        for (int r = 0; r < 16; ++r) {
            int q = qb * 32 + (r & 3) + 8 * (r >> 2) + 4 * hi;
            *(unsigned short*)((char*)Asm + q * 512 + head * 64 + lo * 2) = f2bf(o[qb][r]);
        }
    __builtin_amdgcn_s_barrier();
    {
        unsigned short* ob = out + ((size_t)widx << 6) * 256;
#pragma unroll
        for (int i = 0; i < 4; ++i) {
            int u = tid + (i << 9);
            uint4 vv = *(const uint4*)((const char*)Asm + (size_t)u * 16);
            *(uint4*)(ob + (size_t)(u >> 5) * 256 + (u & 31) * 8) = vv;
        }
    }
#undef AREAD
#undef DANCE
}

// ---------------------------------------------------------------------------
extern "C" void kernel_launch(void* const* d_in, const int* in_sizes, int n_in,
                              void* d_out, int out_size, void* d_ws, size_t ws_size,
                              hipStream_t stream)
{
    const float* x      = (const float*)d_in[0];
    const float* ln1_g  = (const float*)d_in[1];
    const float* ln1_b  = (const float*)d_in[2];
    const float* qkv_w  = (const float*)d_in[3];
    const float* qkv_b  = (const float*)d_in[4];
    const float* proj_w = (const float*)d_in[5];
    const float* proj_b = (const float*)d_in[6];
    const float* table  = (const float*)d_in[7];
    const float* ln2_g  = (const float*)d_in[8];
    const float* ln2_b  = (const float*)d_in[9];
    const float* w1     = (const float*)d_in[10];
    const float* b1     = (const float*)d_in[11];
    const float* w2     = (const float*)d_in[12];
    const float* b2     = (const float*)d_in[13];
    const int*   relidx = (const int*)d_in[14];
    float* out = (float*)d_out;

    char* w = (char*)d_ws;
    unsigned short* xw   = (unsigned short*)w;                      // 32MB (ln1out -> ln2out)
    unsigned short* qkvb = (unsigned short*)(w + (32u << 20));      // 128MB (attn_out 32MB -> mlp hidden 128MB)
    unsigned short* h2b  = (unsigned short*)(w + (160u << 20));     // 32MB (bf16 residual stream)
    float*          bexp = (float*)(w + (224u << 20));              // 128KB
    unsigned short* qkvT = (unsigned short*)(w + (224u << 20) + (128u << 10)); // 384KB
    unsigned short* prjT = qkvT + 768 * 256;                        // 128KB
    unsigned short* w1T  = prjT + 256 * 256;                        // 512KB
    unsigned short* w2T  = w1T + 1024 * 256;                        // 512KB

    // 0. weight transposes + bf16 convert + rel-pos bias expand (one kernel)
    prep_kernel<<<896, 256, 0, stream>>>(qkv_w, proj_w, w1, w2,
                                         qkvT, prjT, w1T, w2T,
                                         table, relidx, bexp);
    // 1. LN1 + cyclic shift + window partition (gather) -> xw bf16 [65536,256]
    ln_kernel<0><<<16384, 256, 0, stream>>>(x, ln1_g, ln1_b, xw, 1);
    // 2+3. fused QKV + window attention -> attn_out (qkvb) bf16 [65536,256]
    qkvattn_kernel<<<1024, 512, 0, stream>>>(xw, qkvT, qkv_b, bexp, qkvb);
    // 4. proj GEMM + window-reverse/unshift scatter + residual(x f32) -> h2b bf16
    mgemm_kernel<1, 0, 2, 0, 0><<<512 * 2, 512, 0, stream>>>(
        qkvb, prjT, proj_b, (void*)h2b, x, 65536, 256, 256);
    // 5. LN2 (bf16 in) -> ln2out (reuse xw) bf16
    ln_kernel<1><<<16384, 256, 0, stream>>>(h2b, ln2_g, ln2_b, xw, 0);
    // 6. MLP1 GEMM + GELU -> hidden (reuse qkvb) bf16 [65536,1024]
    mgemm_kernel<1, 1, 0, 0, 0><<<512 * 8, 512, 0, stream>>>(
        xw, w1T, b1, (void*)qkvb, nullptr, 65536, 1024, 256);
    // 7. MLP2 GEMM + residual(h2b bf16) -> d_out f32
    mgemm_kernel<0, 0, 1, 0, 1><<<512 * 2, 512, 0, stream>>>(
        qkvb, w2T, b2, (void*)out, h2b, 65536, 256, 1024);
}